// Round 6
// baseline (936.613 us; speedup 1.0000x reference)
//
#include <hip/hip_runtime.h>
#include <hip/hip_bf16.h>

// Problem constants (fixed by the reference)
constexpr int N_NODES = 50000;
constexpr int N_EDGES = 800000;
constexpr int R_REL   = 8;
constexpr int BASES   = 4;
constexpr int D       = 256;                 // DIN = DH = DOUT
constexpr int KT      = BASES * D + D;       // 1280: 4 basis blocks + self block
constexpr int NKEYS   = N_NODES * R_REL;     // 400000 (dst,rel) buckets
// z layout: k < 1024 -> k = col*4 + b (basis-space aggregate, interleaved)
//           k >= 1024 -> self feature col = k - 1024

typedef __attribute__((ext_vector_type(8))) short bf16x8;
typedef __attribute__((ext_vector_type(4))) float f32x4;

__device__ inline float bfu_lo(unsigned u) { return __uint_as_float(u << 16); }
__device__ inline float bfu_hi(unsigned u) { return __uint_as_float(u & 0xFFFF0000u); }
__device__ inline unsigned short f2bu(float f) {
  __hip_bfloat16 h = __float2bfloat16(f);
  return *reinterpret_cast<unsigned short*>(&h);
}
__device__ inline void store_out(float* p, float v) { *p = v; }
__device__ inline void store_out(__hip_bfloat16* p, float v) { *p = __float2bfloat16(v); }

// async 16B global -> LDS (wave-uniform lds base + lane*16)
__device__ inline void gload_lds16(void* lds, const void* g) {
  __builtin_amdgcn_global_load_lds(
      (const __attribute__((address_space(1))) unsigned*)g,
      (__attribute__((address_space(3))) unsigned*)lds, 16, 0, 0);
}

// ---------------------------------------------------------------------------
// 1. Count per-(dst,rel) edges AND record each edge's rank within its bucket
// ---------------------------------------------------------------------------
__global__ __launch_bounds__(256) void count_rank_kernel(
    const int* __restrict__ ei, const int* __restrict__ et,
    int* __restrict__ cnt, int* __restrict__ rank) {
  int e = blockIdx.x * 256 + threadIdx.x;
  if (e < N_EDGES) {
    int dst = ei[N_EDGES + e];
    int rt  = et[e];
    rank[e] = atomicAdd(&cnt[dst * R_REL + rt], 1);
  }
}

// ---------------------------------------------------------------------------
// 2. Exclusive scan of cnt[400000] -> ecdf (3-phase).
// ---------------------------------------------------------------------------
constexpr int SCAN_B = (NKEYS + 255) / 256;            // 1563 blocks
constexpr int CHUNK  = (SCAN_B + 255) / 256;           // 7 per thread in phaseB

__global__ __launch_bounds__(256) void scan_phaseA(
    const int* __restrict__ cnt, int* __restrict__ bsum) {
  __shared__ int sd[256];
  int tid = threadIdx.x;
  int idx = blockIdx.x * 256 + tid;
  int d = (idx < NKEYS) ? cnt[idx] : 0;
  sd[tid] = d;
  __syncthreads();
  for (int off = 128; off > 0; off >>= 1) {
    if (tid < off) sd[tid] += sd[tid + off];
    __syncthreads();
  }
  if (tid == 0) bsum[blockIdx.x] = sd[0];
}

__global__ __launch_bounds__(256) void scan_phaseB(
    const int* __restrict__ bsum, int* __restrict__ boff,
    int* __restrict__ ecdf) {
  __shared__ int sd[256];
  int tid = threadIdx.x;
  int loc[CHUNK];
  int lsum = 0;
#pragma unroll
  for (int j = 0; j < CHUNK; j++) {
    int i = tid * CHUNK + j;
    loc[j] = (i < SCAN_B) ? bsum[i] : 0;
    lsum += loc[j];
  }
  sd[tid] = lsum;
  __syncthreads();
  for (int off = 1; off < 256; off <<= 1) {
    int t = (tid >= off) ? sd[tid - off] : 0;
    __syncthreads();
    sd[tid] += t;
    __syncthreads();
  }
  int running = sd[tid] - lsum;
#pragma unroll
  for (int j = 0; j < CHUNK; j++) {
    int i = tid * CHUNK + j;
    if (i < SCAN_B) boff[i] = running;
    running += loc[j];
  }
  if (tid == 0) ecdf[NKEYS] = N_EDGES;
}

__global__ __launch_bounds__(256) void scan_phaseC_winv(
    const int* __restrict__ cnt, const int* __restrict__ boff,
    const float* __restrict__ comp1, const float* __restrict__ comp2,
    int* __restrict__ ecdf, float4* __restrict__ wtab1,
    float4* __restrict__ wtab2) {
  __shared__ int sd[256];
  int tid = threadIdx.x;
  int idx = blockIdx.x * 256 + tid;
  int d = (idx < NKEYS) ? cnt[idx] : 0;
  sd[tid] = d;
  __syncthreads();
  for (int off = 1; off < 256; off <<= 1) {
    int t = (tid >= off) ? sd[tid - off] : 0;
    __syncthreads();
    sd[tid] += t;
    __syncthreads();
  }
  if (idx < NKEYS) {
    ecdf[idx] = boff[blockIdx.x] + sd[tid] - d;
    int r = idx & 7;
    float inv = 1.0f / (float)(d > 0 ? d : 1);
    float4 c1 = *(const float4*)(comp1 + r * BASES);
    float4 c2 = *(const float4*)(comp2 + r * BASES);
    wtab1[idx] = make_float4(c1.x * inv, c1.y * inv, c1.z * inv, c1.w * inv);
    wtab2[idx] = make_float4(c2.x * inv, c2.y * inv, c2.z * inv, c2.w * inv);
  }
}

// ---------------------------------------------------------------------------
// 3. Bucket edges (no atomics): pos = ecdf[key] + rank[e]
// ---------------------------------------------------------------------------
__global__ __launch_bounds__(256) void bucket_kernel(
    const int* __restrict__ ei, const int* __restrict__ et,
    const int* __restrict__ rank, const int* __restrict__ ecdf,
    int* __restrict__ packed) {
  int e = blockIdx.x * 256 + threadIdx.x;
  if (e < N_EDGES) {
    int src = ei[e];
    int dst = ei[N_EDGES + e];
    int rt  = et[e];
    int pos = ecdf[dst * R_REL + rt] + rank[e];
    packed[pos] = src | (rt << 20);
  }
}

// ---------------------------------------------------------------------------
// 4. x (fp32) -> bf16, packed as uint pairs
// ---------------------------------------------------------------------------
__global__ __launch_bounds__(256) void convert_kernel(
    const float* __restrict__ x, unsigned* __restrict__ x2) {
  int idx = blockIdx.x * 256 + threadIdx.x;  // over N*128
  if (idx < N_NODES * 128) {
    float2 v = *(const float2*)(x + (size_t)idx * 2);
    x2[idx] = (unsigned)f2bu(v.x) | ((unsigned)f2bu(v.y) << 16);
  }
}

// ---------------------------------------------------------------------------
// 5. Weight build, both layers in one launch (blockIdx.y selects layer).
//    WT[o][k] bf16 (transposed). k<1024: basis[b=k&3][i=k>>2][o]; else root.
// ---------------------------------------------------------------------------
__global__ __launch_bounds__(256) void make_w_kernel(
    const float* __restrict__ basis1, const float* __restrict__ root1,
    __hip_bfloat16* __restrict__ WT1,
    const float* __restrict__ basis2, const float* __restrict__ root2,
    __hip_bfloat16* __restrict__ WT2) {
  const float* basis = blockIdx.y ? basis2 : basis1;
  const float* root  = blockIdx.y ? root2  : root1;
  __hip_bfloat16* WT = blockIdx.y ? WT2 : WT1;
  __shared__ __hip_bfloat16 tile[64][256];
  int k0 = blockIdx.x * 64;
  int tid = threadIdx.x;
#pragma unroll 4
  for (int r = 0; r < 64; r++) {
    int k = k0 + r;
    const float* srow = (k < BASES * D)
        ? basis + ((size_t)(k & 3) * D + (k >> 2)) * D
        : root + (size_t)(k - BASES * D) * D;
    tile[r][tid] = __float2bfloat16(srow[tid]);
  }
  __syncthreads();
  __hip_bfloat16* dst = WT + (size_t)tid * KT + k0;
#pragma unroll
  for (int c = 0; c < 8; c++) {
    union { short s[8]; int4 v; } u;
#pragma unroll
    for (int r = 0; r < 8; r++)
      u.s[r] = *reinterpret_cast<short*>(&tile[c * 8 + r][tid]);
    *(int4*)(dst + c * 8) = u.v;
  }
}

// ---------------------------------------------------------------------------
// 6. Aggregate into basis space. WAVE per node; half-wave per edge: one
//    dwordx4 gather instruction fetches TWO edge rows (64 x 16B = 1 KB).
//    4-pair unroll = 8 edges in flight. shfl_xor(32) cross-half reduce.
// ---------------------------------------------------------------------------
__device__ inline void pair_fma(float acc[BASES][8], uint4 v, float4 w) {
  float f0 = bfu_lo(v.x), f1 = bfu_hi(v.x), f2 = bfu_lo(v.y), f3 = bfu_hi(v.y);
  float f4 = bfu_lo(v.z), f5 = bfu_hi(v.z), f6 = bfu_lo(v.w), f7 = bfu_hi(v.w);
  acc[0][0] += w.x * f0; acc[0][1] += w.x * f1; acc[0][2] += w.x * f2; acc[0][3] += w.x * f3;
  acc[0][4] += w.x * f4; acc[0][5] += w.x * f5; acc[0][6] += w.x * f6; acc[0][7] += w.x * f7;
  acc[1][0] += w.y * f0; acc[1][1] += w.y * f1; acc[1][2] += w.y * f2; acc[1][3] += w.y * f3;
  acc[1][4] += w.y * f4; acc[1][5] += w.y * f5; acc[1][6] += w.y * f6; acc[1][7] += w.y * f7;
  acc[2][0] += w.z * f0; acc[2][1] += w.z * f1; acc[2][2] += w.z * f2; acc[2][3] += w.z * f3;
  acc[2][4] += w.z * f4; acc[2][5] += w.z * f5; acc[2][6] += w.z * f6; acc[2][7] += w.z * f7;
  acc[3][0] += w.w * f0; acc[3][1] += w.w * f1; acc[3][2] += w.w * f2; acc[3][3] += w.w * f3;
  acc[3][4] += w.w * f4; acc[3][5] += w.w * f5; acc[3][6] += w.w * f6; acc[3][7] += w.w * f7;
}

__global__ __launch_bounds__(256) void aggregate_kernel(
    const uint4* __restrict__ x4,      // bf16 features, [N][32] 16B chunks
    const int* __restrict__ packed,
    const int* __restrict__ ecdf,      // node n edges: [ecdf[8n], ecdf[8n+8])
    const float4* __restrict__ wtab,   // [N*8] per-(node,rel) basis weights
    __hip_bfloat16* __restrict__ zA)   // [N][KT]
{
  int tid = threadIdx.x;
  int wave = tid >> 6, lane = tid & 63;
  int half = lane >> 5, sl = lane & 31;
  int n = blockIdx.x * 4 + wave;       // wave-uniform node
  int s = ecdf[n * R_REL], e = ecdf[n * R_REL + R_REL];
  const float4* wt = wtab + (size_t)n * R_REL;

  float acc[BASES][8] = {};            // [b][j], col = 8*sl + j
  int base = s;

  // main loop: 4 pairs = 8 edges, 4 gather instructions in flight
  for (; base + 8 <= e; base += 8) {
    int p[4];
#pragma unroll
    for (int q = 0; q < 4; q++) p[q] = packed[base + 2 * q + half];
    uint4 v[4];
#pragma unroll
    for (int q = 0; q < 4; q++)
      v[q] = x4[(size_t)(p[q] & 0xFFFFF) * 32 + sl];
    float4 w[4];
#pragma unroll
    for (int q = 0; q < 4; q++) w[q] = wt[p[q] >> 20];
#pragma unroll
    for (int q = 0; q < 4; q++) pair_fma(acc, v[q], w[q]);
  }

  // tail: one pair at a time; odd last edge -> upper half gets zero weight
  for (; base < e; base += 2) {
    int rem = e - base;                // wave-uniform, >= 1
    int idx = base + ((rem > 1) ? half : 0);
    int p = packed[idx];
    uint4 v = x4[(size_t)(p & 0xFFFFF) * 32 + sl];
    float4 w = wt[p >> 20];
    if (half && rem == 1) w = make_float4(0.f, 0.f, 0.f, 0.f);
    pair_fma(acc, v, w);
  }

  // cross-half reduce: both halves end with the full sum
#pragma unroll
  for (int b = 0; b < BASES; b++)
#pragma unroll
    for (int j = 0; j < 8; j++)
      acc[b][j] += __shfl_xor(acc[b][j], 32, 64);

  // store: col c = 8*sl + j -> k = 4c + b; half h packs j in [4h, 4h+4)
  __hip_bfloat16* zrow = zA + (size_t)n * KT;
  union { unsigned short s[16]; int4 v[2]; } u;
#pragma unroll
  for (int jj = 0; jj < 4; jj++)
#pragma unroll
    for (int b = 0; b < BASES; b++)
      u.s[jj * 4 + b] = f2bu(acc[b][4 * half + jj]);
  *(int4*)(zrow + 32 * sl + 16 * half) = u.v[0];
  *(int4*)(zrow + 32 * sl + 16 * half + 8) = u.v[1];

  // self block: straight bf16 copy
  const unsigned* x2 = (const unsigned*)x4;
  uint2 sv = *(const uint2*)(x2 + (size_t)n * 128 + lane * 2);
  *(uint2*)((unsigned*)(zrow + BASES * D) + lane * 2) = sv;
}

// ---------------------------------------------------------------------------
// 7. GEMM: C[M,256] = A[M,1280](bf16) @ WT^T + bias. BM=128 x BN=256 (A read
//    once), BK=64 (20 iters, 6 KB in flight per wave per iter), 512 thr /
//    8 waves. XOR-swizzled LDS (chunk c ^ (row&7)) -> conflict-free ds_read,
//    compatible with global_load_lds' fixed base+lane*16 write pattern.
// ---------------------------------------------------------------------------
#define BM 128
#define BN 256
#define BK 64   // elems; LDS row = 128 B = 8 chunks x 16 B

template <bool RELU, typename OutT>
__global__ __launch_bounds__(512) void gemm_kernel(
    const __hip_bfloat16* __restrict__ A,   // [M, KT]
    const __hip_bfloat16* __restrict__ Bt,  // [256, KT] (transposed weights)
    const float* __restrict__ bias, OutT* __restrict__ C, int M) {
  __shared__ __align__(16) __hip_bfloat16 As[BM * BK];  // 16 KB
  __shared__ __align__(16) __hip_bfloat16 Bs[BN * BK];  // 32 KB
  int tid = threadIdx.x;
  int m0 = blockIdx.x * BM;
  int wave = tid >> 6, lane = tid & 63;
  int wm = wave & 1, wn = wave >> 1;   // 2(m) x 4(n) wave grid, 64x64 each
  int l15 = lane & 15, quad = lane >> 4;

  // Staging: each issue covers 8 rows x 128 B. Lane l -> row base + (l>>3),
  // swizzled chunk c = (l&7) ^ (l>>3); LDS dest = rowbase*BK + lane*8 elems
  // (hardware adds lane*16B to the wave-uniform base).
  int lr = lane >> 3;                  // 0..7
  int lc = (lane & 7) ^ lr;            // swizzled chunk 0..7
  int colE = lc * 8;                   // elem offset within BK window
  int ra0 = min(m0 + wave * 16 + lr, M - 1);      // clamp; epilogue masks
  int ra1 = min(m0 + wave * 16 + 8 + lr, M - 1);
  const __hip_bfloat16* gA0 = A + (size_t)ra0 * KT + colE;
  const __hip_bfloat16* gA1 = A + (size_t)ra1 * KT + colE;
  __hip_bfloat16* lA0 = As + (wave * 16) * BK;
  __hip_bfloat16* lA1 = As + (wave * 16 + 8) * BK;
  const __hip_bfloat16* gB[4];
  __hip_bfloat16* lB[4];
#pragma unroll
  for (int o = 0; o < 4; o++) {
    gB[o] = Bt + (size_t)(wave * 32 + o * 8 + lr) * KT + colE;
    lB[o] = Bs + (wave * 32 + o * 8) * BK;
  }

  f32x4 acc[4][4] = {};

  for (int k0 = 0; k0 < KT; k0 += BK) {
    gload_lds16(lA0, gA0 + k0);
    gload_lds16(lA1, gA1 + k0);
#pragma unroll
    for (int o = 0; o < 4; o++) gload_lds16(lB[o], gB[o] + k0);
    __syncthreads();

#pragma unroll
    for (int ks = 0; ks < 2; ks++) {
      int cA = (((ks * 4 + quad) ^ (l15 & 7)) << 3);  // swizzled chunk offset
      bf16x8 af[4], bfr[4];
#pragma unroll
      for (int mt = 0; mt < 4; mt++)
        af[mt] = *(const bf16x8*)(As + (wm * 64 + mt * 16 + l15) * BK + cA);
#pragma unroll
      for (int nt = 0; nt < 4; nt++)
        bfr[nt] = *(const bf16x8*)(Bs + (wn * 64 + nt * 16 + l15) * BK + cA);
#pragma unroll
      for (int mt = 0; mt < 4; mt++)
#pragma unroll
        for (int nt = 0; nt < 4; nt++)
          acc[mt][nt] = __builtin_amdgcn_mfma_f32_16x16x32_bf16(
              af[mt], bfr[nt], acc[mt][nt], 0, 0, 0);
    }
    __syncthreads();
  }

  // epilogue: C/D layout col = lane&15, row = quad*4 + reg
#pragma unroll
  for (int nt = 0; nt < 4; nt++) {
    int cg = wn * 64 + nt * 16 + l15;
    float bv = bias[cg];
#pragma unroll
    for (int mt = 0; mt < 4; mt++) {
#pragma unroll
      for (int r = 0; r < 4; r++) {
        int rg = m0 + wm * 64 + mt * 16 + quad * 4 + r;
        if (rg < M) {
          float v = acc[mt][nt][r] + bv;
          if (RELU) v = fmaxf(v, 0.f);
          store_out(C + (size_t)rg * D + cg, v);
        }
      }
    }
  }
}

// ---------------------------------------------------------------------------
// Launch
// ---------------------------------------------------------------------------
static inline char* carve(char*& p, size_t bytes) {
  char* r = p;
  p += (bytes + 255) & ~(size_t)255;
  return r;
}

extern "C" void kernel_launch(void* const* d_in, const int* in_sizes, int n_in,
                              void* d_out, int out_size, void* d_ws,
                              size_t ws_size, hipStream_t stream) {
  const float* x      = (const float*)d_in[0];
  const int*   ei     = (const int*)d_in[1];
  const int*   et     = (const int*)d_in[2];
  const float* basis1 = (const float*)d_in[3];
  const float* comp1  = (const float*)d_in[4];
  const float* root1  = (const float*)d_in[5];
  const float* bias1  = (const float*)d_in[6];
  const float* basis2 = (const float*)d_in[7];
  const float* comp2  = (const float*)d_in[8];
  const float* root2  = (const float*)d_in[9];
  const float* bias2  = (const float*)d_in[10];
  float* out = (float*)d_out;

  char* ws = (char*)d_ws;
  int* cnt    = (int*)carve(ws, (size_t)NKEYS * 4);
  int* ecdf   = (int*)carve(ws, (size_t)(NKEYS + 1) * 4);
  int* rank   = (int*)carve(ws, (size_t)N_EDGES * 4);
  int* bsum   = (int*)carve(ws, (size_t)SCAN_B * 4);
  int* boff   = (int*)carve(ws, (size_t)SCAN_B * 4);
  int* packed = (int*)carve(ws, (size_t)N_EDGES * 4);
  float4* wtab1 = (float4*)carve(ws, (size_t)NKEYS * 16);
  float4* wtab2 = (float4*)carve(ws, (size_t)NKEYS * 16);
  __hip_bfloat16* WT1 = (__hip_bfloat16*)carve(ws, (size_t)D * KT * 2);
  __hip_bfloat16* WT2 = (__hip_bfloat16*)carve(ws, (size_t)D * KT * 2);
  unsigned* xb = (unsigned*)carve(ws, (size_t)N_NODES * D * 2);   // bf16 x
  __hip_bfloat16* h = (__hip_bfloat16*)carve(ws, (size_t)N_NODES * D * 2);
  __hip_bfloat16* zA = (__hip_bfloat16*)carve(ws, (size_t)N_NODES * KT * 2);

  const int EB = (N_EDGES + 255) / 256;   // 3125
  const int CB = (N_NODES * 128 + 255) / 256;

  hipMemsetAsync(cnt, 0, (size_t)NKEYS * 4, stream);

  count_rank_kernel<<<EB, 256, 0, stream>>>(ei, et, cnt, rank);
  scan_phaseA<<<SCAN_B, 256, 0, stream>>>(cnt, bsum);
  scan_phaseB<<<1, 256, 0, stream>>>(bsum, boff, ecdf);
  scan_phaseC_winv<<<SCAN_B, 256, 0, stream>>>(cnt, boff, comp1, comp2,
                                               ecdf, wtab1, wtab2);
  bucket_kernel<<<EB, 256, 0, stream>>>(ei, et, rank, ecdf, packed);

  convert_kernel<<<CB, 256, 0, stream>>>(x, xb);
  make_w_kernel<<<dim3(KT / 64, 2), 256, 0, stream>>>(basis1, root1, WT1,
                                                      basis2, root2, WT2);

  const int GB = (N_NODES + BM - 1) / BM;  // 391 blocks
  const int AB = (N_NODES + 3) / 4;        // 12500 blocks, wave per node

  // Layer 1
  aggregate_kernel<<<AB, 256, 0, stream>>>((const uint4*)xb, packed, ecdf,
                                           wtab1, zA);
  gemm_kernel<true, __hip_bfloat16><<<GB, 512, 0, stream>>>(zA, WT1, bias1, h,
                                                            N_NODES);

  // Layer 2 (h is bf16 [N][256] — same 16B-chunk view as xb)
  aggregate_kernel<<<AB, 256, 0, stream>>>((const uint4*)h, packed, ecdf,
                                           wtab2, zA);
  gemm_kernel<false, float><<<GB, 512, 0, stream>>>(zA, WT2, bias2, out,
                                                    N_NODES);
}